// Round 4
// baseline (96.498 us; speedup 1.0000x reference)
//
#include <hip/hip_runtime.h>
#include <math.h>

// Problem constants (fixed by reference setup_inputs)
#define BSZ   16
#define NA    3
#define NH    80
#define NW    80
#define NC    80
#define HW    (NH * NW)                 // 6400
#define CELLS (BSZ * NA * NH * NW)      // 307200
#define EPSL  1e-07f
#define BLK   256

// Class-BCE decomposition: 4 cells/thread, 16 channels/chunk, 5 chunks
#define CPT_C  4
#define NSPLIT 5
#define CCH    (NC / NSPLIT)            // 16 channels
#define NSEG   (CELLS / CPT_C / BLK)    // 300 segments
#define NBLK_CLS (NSEG * NSPLIT)        // 1500

// Box decomposition: 2 cells/thread
#define CPT_B  2
#define NBLK_BOX (CELLS / CPT_B / BLK)  // 600
#define NBLK_TOT (NBLK_CLS + NBLK_BOX)  // 2100

// ws layout: [0 .. NBLK_BOX*4)   box partials (xy, wh, iou, conf)
//            [WS_CLS .. +NBLK_CLS) class partials
#define WS_CLS (NBLK_BOX * 4)           // 2400

#define L2E 1.4426950408889634f
#define LN2 0.6931471805599453f

__device__ __forceinline__ float fexp2(float x) { return __builtin_amdgcn_exp2f(x); }
__device__ __forceinline__ float flog2(float x) { return __builtin_amdgcn_logf(x); }
__device__ __forceinline__ float frcp(float x)  { return __builtin_amdgcn_rcpf(x); }

// max(z,0) - z*t + log1p(exp(-|z|)) via HW exp2/log2
__device__ __forceinline__ float bce_fast(float z, float t) {
    const float e  = fexp2(-fabsf(z) * L2E);
    const float sp = LN2 * flog2(1.0f + e);
    return fmaxf(z, 0.0f) - z * t + sp;
}

__device__ __forceinline__ float sigmoid_fast(float z) {
    return frcp(1.0f + fexp2(-z * L2E));
}

__global__ __launch_bounds__(BLK, 5) void yolo_loss_main(
    const float* __restrict__ input,
    const float* __restrict__ mask,
    const float* __restrict__ obj_mask,
    const float* __restrict__ tx,
    const float* __restrict__ ty,
    const float* __restrict__ tw,
    const float* __restrict__ th,
    const float* __restrict__ tgt_scale,
    const float* __restrict__ tcls,
    float* __restrict__ ws)
{
    __shared__ float red[4][4];
    const int lane = threadIdx.x & 63;
    const int wid  = threadIdx.x >> 6;
    const int bid  = blockIdx.x;

    if (bid < NBLK_CLS) {
        // ---------------- class-BCE path (block-uniform) ----------------
        const int cc  = bid % NSPLIT;               // chunk 0..4
        const int seg = bid / NSPLIT;               // 0..299
        const int t   = seg * BLK + threadIdx.x;    // [0, CELLS/4)
        const int hw    = (t % (HW / CPT_C)) * CPT_C;
        const int plane = t / (HW / CPT_C);
        const int cb    = plane * HW + hw;

        const float* zb  = input + (size_t)plane * (5 + NC) * HW + hw
                         + (size_t)(5 + cc * CCH) * HW;
        const float* tcb = tcls + (size_t)cb * NC + cc * CCH;

        float m[4];
        *(float4*)m = *(const float4*)(mask + cb);

        float accc[4] = {0.f, 0.f, 0.f, 0.f};
        #pragma unroll 2
        for (int c4 = 0; c4 < CCH / 4; ++c4) {      // 4 groups of 4 channels
            float zj[4][4];  // [channel j][cell k]
            #pragma unroll
            for (int j = 0; j < 4; ++j)
                *(float4*)zj[j] = *(const float4*)(zb + (size_t)(4 * c4 + j) * HW);
            float tk[4][4];  // [cell k][channel j]
            #pragma unroll
            for (int k = 0; k < 4; ++k)
                *(float4*)tk[k] = *(const float4*)(tcb + k * NC + 4 * c4);
            #pragma unroll
            for (int j = 0; j < 4; ++j)
                #pragma unroll
                for (int k = 0; k < 4; ++k)
                    accc[k] += bce_fast(zj[j][k], tk[k][j]);
        }
        float v = m[0] * accc[0] + m[1] * accc[1] + m[2] * accc[2] + m[3] * accc[3];

        #pragma unroll
        for (int off = 32; off > 0; off >>= 1)
            v += __shfl_down(v, off, 64);
        if (lane == 0) red[wid][0] = v;
        __syncthreads();
        if (threadIdx.x == 0)
            ws[WS_CLS + bid] = red[0][0] + red[1][0] + red[2][0] + red[3][0];

    } else {
        // ---------------- box/conf/CIOU path (block-uniform) ----------------
        const int bbid = bid - NBLK_CLS;
        const int t    = bbid * BLK + threadIdx.x;  // [0, CELLS/2)
        const int hw    = (t % (HW / CPT_B)) * CPT_B;
        const int plane = t / (HW / CPT_B);
        const int cb    = plane * HW + hw;

        const float* pbase = input + (size_t)plane * (5 + NC) * HW + hw;

        float zx[2], zy[2], pw[2], ph[2], zc[2];
        *(float2*)zx = *(const float2*)(pbase + 0 * HW);
        *(float2*)zy = *(const float2*)(pbase + 1 * HW);
        *(float2*)pw = *(const float2*)(pbase + 2 * HW);
        *(float2*)ph = *(const float2*)(pbase + 3 * HW);
        *(float2*)zc = *(const float2*)(pbase + 4 * HW);

        float m[2], om[2], gx[2], gy[2], gw[2], gh[2], ts[2];
        *(float2*)m  = *(const float2*)(mask      + cb);
        *(float2*)om = *(const float2*)(obj_mask  + cb);
        *(float2*)gx = *(const float2*)(tx        + cb);
        *(float2*)gy = *(const float2*)(ty        + cb);
        *(float2*)gw = *(const float2*)(tw        + cb);
        *(float2*)gh = *(const float2*)(th        + cb);
        *(float2*)ts = *(const float2*)(tgt_scale + cb);

        float s_xy = 0.f, s_wh = 0.f, s_iou = 0.f, s_conf = 0.f;

        #pragma unroll
        for (int k = 0; k < CPT_B; ++k) {
            const float x = sigmoid_fast(zx[k]);
            const float y = sigmoid_fast(zy[k]);

            s_xy  += ts[k] * (fabsf(x - gx[k]) + fabsf(y - gy[k]));
            s_wh  += ts[k] * (fabsf(pw[k] - gw[k]) + fabsf(ph[k] - gh[k]));
            s_conf += om[k] * bce_fast(zc[k], m[k]);

            const float p_x1 = x - pw[k] * 0.5f, p_x2 = x + pw[k] * 0.5f;
            const float p_y1 = y - ph[k] * 0.5f, p_y2 = y + ph[k] * 0.5f;
            const float g_x1 = gx[k] - gw[k] * 0.5f, g_x2 = gx[k] + gw[k] * 0.5f;
            const float g_y1 = gy[k] - gh[k] * 0.5f, g_y2 = gy[k] + gh[k] * 0.5f;

            const float iw = fmaxf(fminf(p_x2, g_x2) - fmaxf(p_x1, g_x1), 0.0f);
            const float ih = fmaxf(fminf(p_y2, g_y2) - fmaxf(p_y1, g_y1), 0.0f);
            const float inter = iw * ih;
            const float uni   = pw[k] * ph[k] + gw[k] * gh[k] - inter + EPSL;
            const float iou   = inter * frcp(uni);

            const float cw = fmaxf(p_x2, g_x2) - fminf(p_x1, g_x1);
            const float ch = fmaxf(p_y2, g_y2) - fminf(p_y1, g_y1);
            const float c2 = cw * cw + ch * ch + EPSL;
            const float rho2 = (x - gx[k]) * (x - gx[k]) + (y - gy[k]) * (y - gy[k]);

            const float da = atanf(gw[k] * frcp(gh[k] + EPSL))
                           - atanf(pw[k] * frcp(ph[k] + EPSL));
            const float v  = (4.0f / (float)(M_PI * M_PI)) * da * da;
            const float alpha = v * frcp(v - iou + 1.0f + EPSL);

            const float lbox = 1.0f - (iou - (rho2 * frcp(c2) + v * alpha));
            s_iou += m[k] * ts[k] * lbox;
        }

        float vals[4] = { s_xy, s_wh, s_iou, s_conf };
        #pragma unroll
        for (int j = 0; j < 4; ++j) {
            float v = vals[j];
            #pragma unroll
            for (int off = 32; off > 0; off >>= 1)
                v += __shfl_down(v, off, 64);
            vals[j] = v;
        }
        if (lane == 0) {
            #pragma unroll
            for (int j = 0; j < 4; ++j) red[wid][j] = vals[j];
        }
        __syncthreads();
        if (threadIdx.x == 0) {
            #pragma unroll
            for (int j = 0; j < 4; ++j)
                ws[(size_t)bbid * 4 + j] =
                    red[0][j] + red[1][j] + red[2][j] + red[3][j];
        }
    }
}

// Deterministic final reduction: one block, fixed order -> identical every replay.
__global__ __launch_bounds__(BLK) void yolo_loss_final(
    const float* __restrict__ ws, float* __restrict__ out)
{
    __shared__ float red[4];
    const int lane = threadIdx.x & 63;
    const int wid  = threadIdx.x >> 6;
    const float scale4[4] = { 1.0f / (BSZ * BSZ), 1.0f / (BSZ * BSZ),
                              1.0f / BSZ, 1.0f / BSZ };

    // box partials: 4 components
    for (int j = 0; j < 4; ++j) {
        float v = 0.f;
        for (int i = threadIdx.x; i < NBLK_BOX; i += BLK)
            v += ws[(size_t)i * 4 + j];
        #pragma unroll
        for (int off = 32; off > 0; off >>= 1)
            v += __shfl_down(v, off, 64);
        if (lane == 0) red[wid] = v;
        __syncthreads();
        if (threadIdx.x == 0)
            out[j] = (red[0] + red[1] + red[2] + red[3]) * scale4[j];
        __syncthreads();
    }
    // class partials
    {
        float v = 0.f;
        for (int i = threadIdx.x; i < NBLK_CLS; i += BLK)
            v += ws[WS_CLS + i];
        #pragma unroll
        for (int off = 32; off > 0; off >>= 1)
            v += __shfl_down(v, off, 64);
        if (lane == 0) red[wid] = v;
        __syncthreads();
        if (threadIdx.x == 0)
            out[4] = (red[0] + red[1] + red[2] + red[3]) * (1.0f / BSZ);
    }
}

extern "C" void kernel_launch(void* const* d_in, const int* in_sizes, int n_in,
                              void* d_out, int out_size, void* d_ws, size_t ws_size,
                              hipStream_t stream) {
    const float* input     = (const float*)d_in[0];
    const float* mask      = (const float*)d_in[1];
    const float* obj_mask  = (const float*)d_in[2];
    const float* tx        = (const float*)d_in[3];
    const float* ty        = (const float*)d_in[4];
    const float* tw        = (const float*)d_in[5];
    const float* th        = (const float*)d_in[6];
    const float* tgt_scale = (const float*)d_in[7];
    const float* tcls      = (const float*)d_in[8];
    float* out = (float*)d_out;
    float* ws  = (float*)d_ws;   // needs (2400 + 1500)*4 = 15600 bytes

    yolo_loss_main<<<NBLK_TOT, BLK, 0, stream>>>(
        input, mask, obj_mask, tx, ty, tw, th, tgt_scale, tcls, ws);
    yolo_loss_final<<<1, BLK, 0, stream>>>(ws, out);
}

// Round 5
// 71.924 us; speedup vs baseline: 1.3417x; 1.3417x over previous
//
#include <hip/hip_runtime.h>
#include <math.h>

// Problem constants (fixed by reference setup_inputs)
#define BSZ   16
#define NA    3
#define NH    80
#define NW    80
#define NC    80
#define HW    (NH * NW)                 // 6400
#define CELLS (BSZ * NA * NH * NW)      // 307200
#define EPSL  1e-07f
#define BLK   256

#define NBLK_CLS (CELLS / BLK)          // 1200: one cell per thread, all 80 ch
#define NBLK_BOX (CELLS / BLK)          // 1200: one cell per thread
#define NBLK_TOT (NBLK_CLS + NBLK_BOX)  // 2400

// ws layout: [0 .. NBLK_BOX*4)           box partials (xy, wh, iou, conf)
//            [WS_CLS .. WS_CLS+NBLK_CLS) class partials
#define WS_CLS (NBLK_BOX * 4)           // 4800

#define L2E 1.4426950408889634f
#define LN2 0.6931471805599453f

__device__ __forceinline__ float fexp2(float x) { return __builtin_amdgcn_exp2f(x); }
__device__ __forceinline__ float flog2(float x) { return __builtin_amdgcn_logf(x); }
__device__ __forceinline__ float frcp(float x)  { return __builtin_amdgcn_rcpf(x); }

// max(z,0) - z*t + log1p(exp(-|z|)) via HW exp2/log2
__device__ __forceinline__ float bce_fast(float z, float t) {
    const float e  = fexp2(-fabsf(z) * L2E);
    const float sp = LN2 * flog2(1.0f + e);
    return fmaxf(z, 0.0f) - z * t + sp;
}

__device__ __forceinline__ float sigmoid_fast(float z) {
    return frcp(1.0f + fexp2(-z * L2E));
}

__global__ __launch_bounds__(BLK, 8) void yolo_loss_main(
    const float* __restrict__ input,
    const float* __restrict__ mask,
    const float* __restrict__ obj_mask,
    const float* __restrict__ tx,
    const float* __restrict__ ty,
    const float* __restrict__ tw,
    const float* __restrict__ th,
    const float* __restrict__ tgt_scale,
    const float* __restrict__ tcls,
    float* __restrict__ ws)
{
    __shared__ float red[4][4];
    const int lane = threadIdx.x & 63;
    const int wid  = threadIdx.x >> 6;
    const int bid  = blockIdx.x;

    if (bid < NBLK_CLS) {
        // ------- class-BCE path: one cell per thread, all 80 channels -------
        const int cell  = bid * BLK + threadIdx.x;      // adjacent lanes: adjacent hw
        const int hw    = cell % HW;                    // BLK divides HW -> no plane split
        const int plane = cell / HW;

        // z: input[plane, 5+c, hw] — per channel, lanes coalesce to 256 B
        const float* zb = input + (size_t)plane * (5 + NC) * HW + (size_t)5 * HW + hw;
        // t: tcls[cell, 0..80) — 320 B contiguous per lane, 16 B aligned
        const float* tcb = tcls + (size_t)cell * NC;

        float acc = 0.f;
        #pragma unroll 2
        for (int g = 0; g < NC / 4; ++g) {              // 20 groups of 4 channels
            const float4 t4 = *(const float4*)(tcb + 4 * g);
            const float z0 = zb[(size_t)(4 * g + 0) * HW];
            const float z1 = zb[(size_t)(4 * g + 1) * HW];
            const float z2 = zb[(size_t)(4 * g + 2) * HW];
            const float z3 = zb[(size_t)(4 * g + 3) * HW];
            acc += bce_fast(z0, t4.x);
            acc += bce_fast(z1, t4.y);
            acc += bce_fast(z2, t4.z);
            acc += bce_fast(z3, t4.w);
        }
        float v = mask[cell] * acc;

        #pragma unroll
        for (int off = 32; off > 0; off >>= 1)
            v += __shfl_down(v, off, 64);
        if (lane == 0) red[wid][0] = v;
        __syncthreads();
        if (threadIdx.x == 0)
            ws[WS_CLS + bid] = red[0][0] + red[1][0] + red[2][0] + red[3][0];

    } else {
        // ------- box/conf/CIOU path: one cell per thread -------
        const int bbid  = bid - NBLK_CLS;
        const int cell  = bbid * BLK + threadIdx.x;
        const int hw    = cell % HW;
        const int plane = cell / HW;

        const float* pbase = input + (size_t)plane * (5 + NC) * HW + hw;

        const float zx = pbase[0 * HW];
        const float zy = pbase[1 * HW];
        const float pw = pbase[2 * HW];
        const float ph = pbase[3 * HW];
        const float zc = pbase[4 * HW];

        const float m  = mask[cell];
        const float om = obj_mask[cell];
        const float gx = tx[cell];
        const float gy = ty[cell];
        const float gw = tw[cell];
        const float gh = th[cell];
        const float ts = tgt_scale[cell];

        const float x = sigmoid_fast(zx);
        const float y = sigmoid_fast(zy);

        float s_xy  = ts * (fabsf(x - gx) + fabsf(y - gy));
        float s_wh  = ts * (fabsf(pw - gw) + fabsf(ph - gh));
        float s_conf = om * bce_fast(zc, m);
        float s_iou;
        {
            const float p_x1 = x - pw * 0.5f, p_x2 = x + pw * 0.5f;
            const float p_y1 = y - ph * 0.5f, p_y2 = y + ph * 0.5f;
            const float g_x1 = gx - gw * 0.5f, g_x2 = gx + gw * 0.5f;
            const float g_y1 = gy - gh * 0.5f, g_y2 = gy + gh * 0.5f;

            const float iw = fmaxf(fminf(p_x2, g_x2) - fmaxf(p_x1, g_x1), 0.0f);
            const float ih = fmaxf(fminf(p_y2, g_y2) - fmaxf(p_y1, g_y1), 0.0f);
            const float inter = iw * ih;
            const float uni   = pw * ph + gw * gh - inter + EPSL;
            const float iou   = inter * frcp(uni);

            const float cw = fmaxf(p_x2, g_x2) - fminf(p_x1, g_x1);
            const float ch = fmaxf(p_y2, g_y2) - fminf(p_y1, g_y1);
            const float c2 = cw * cw + ch * ch + EPSL;
            const float rho2 = (x - gx) * (x - gx) + (y - gy) * (y - gy);

            const float da = atanf(gw * frcp(gh + EPSL))
                           - atanf(pw * frcp(ph + EPSL));
            const float v  = (4.0f / (float)(M_PI * M_PI)) * da * da;
            const float alpha = v * frcp(v - iou + 1.0f + EPSL);

            const float lbox = 1.0f - (iou - (rho2 * frcp(c2) + v * alpha));
            s_iou = m * ts * lbox;
        }

        float vals[4] = { s_xy, s_wh, s_iou, s_conf };
        #pragma unroll
        for (int j = 0; j < 4; ++j) {
            float v = vals[j];
            #pragma unroll
            for (int off = 32; off > 0; off >>= 1)
                v += __shfl_down(v, off, 64);
            vals[j] = v;
        }
        if (lane == 0) {
            #pragma unroll
            for (int j = 0; j < 4; ++j) red[wid][j] = vals[j];
        }
        __syncthreads();
        if (threadIdx.x == 0) {
            #pragma unroll
            for (int j = 0; j < 4; ++j)
                ws[(size_t)bbid * 4 + j] =
                    red[0][j] + red[1][j] + red[2][j] + red[3][j];
        }
    }
}

// Deterministic final reduction: one block, fixed order -> identical every replay.
__global__ __launch_bounds__(BLK) void yolo_loss_final(
    const float* __restrict__ ws, float* __restrict__ out)
{
    __shared__ float red[4];
    const int lane = threadIdx.x & 63;
    const int wid  = threadIdx.x >> 6;
    const float scale4[4] = { 1.0f / (BSZ * BSZ), 1.0f / (BSZ * BSZ),
                              1.0f / BSZ, 1.0f / BSZ };

    for (int j = 0; j < 4; ++j) {
        float v = 0.f;
        for (int i = threadIdx.x; i < NBLK_BOX; i += BLK)
            v += ws[(size_t)i * 4 + j];
        #pragma unroll
        for (int off = 32; off > 0; off >>= 1)
            v += __shfl_down(v, off, 64);
        if (lane == 0) red[wid] = v;
        __syncthreads();
        if (threadIdx.x == 0)
            out[j] = (red[0] + red[1] + red[2] + red[3]) * scale4[j];
        __syncthreads();
    }
    {
        float v = 0.f;
        for (int i = threadIdx.x; i < NBLK_CLS; i += BLK)
            v += ws[WS_CLS + i];
        #pragma unroll
        for (int off = 32; off > 0; off >>= 1)
            v += __shfl_down(v, off, 64);
        if (lane == 0) red[wid] = v;
        __syncthreads();
        if (threadIdx.x == 0)
            out[4] = (red[0] + red[1] + red[2] + red[3]) * (1.0f / BSZ);
    }
}

extern "C" void kernel_launch(void* const* d_in, const int* in_sizes, int n_in,
                              void* d_out, int out_size, void* d_ws, size_t ws_size,
                              hipStream_t stream) {
    const float* input     = (const float*)d_in[0];
    const float* mask      = (const float*)d_in[1];
    const float* obj_mask  = (const float*)d_in[2];
    const float* tx        = (const float*)d_in[3];
    const float* ty        = (const float*)d_in[4];
    const float* tw        = (const float*)d_in[5];
    const float* th        = (const float*)d_in[6];
    const float* tgt_scale = (const float*)d_in[7];
    const float* tcls      = (const float*)d_in[8];
    float* out = (float*)d_out;
    float* ws  = (float*)d_ws;   // needs (4800 + 1200)*4 = 24000 bytes

    yolo_loss_main<<<NBLK_TOT, BLK, 0, stream>>>(
        input, mask, obj_mask, tx, ty, tw, th, tgt_scale, tcls, ws);
    yolo_loss_final<<<1, BLK, 0, stream>>>(ws, out);
}

// Round 6
// 44.574 us; speedup vs baseline: 2.1649x; 1.6136x over previous
//
#include <hip/hip_runtime.h>
#include <math.h>

// Problem constants (fixed by reference setup_inputs)
#define BSZ   16
#define NA    3
#define NH    80
#define NW    80
#define NC    80
#define HW    (NH * NW)                 // 6400
#define CELLS (BSZ * NA * NH * NW)      // 307200
#define EPSL  1e-07f
#define BLK   256

// Class path: 64 cells per 256-thread block, 4 lanes per cell (20 ch each).
#define CLS_CB   64
#define NBLK_CLS (CELLS / CLS_CB)       // 4800
#define NBLK_BOX (CELLS / BLK)          // 1200
#define NBLK_TOT (NBLK_CLS + NBLK_BOX)  // 6000
#define PADS     65                     // LDS row stride (words) for tl2[ch][cell]

// ws layout: [0 .. NBLK_BOX*4)            box partials (xy, wh, iou, conf)
//            [WS_CLS .. WS_CLS+NBLK_CLS)  class partials
#define WS_CLS (NBLK_BOX * 4)           // 4800

#define L2E 1.4426950408889634f
#define LN2 0.6931471805599453f

__device__ __forceinline__ float fexp2(float x) { return __builtin_amdgcn_exp2f(x); }
__device__ __forceinline__ float flog2(float x) { return __builtin_amdgcn_logf(x); }
__device__ __forceinline__ float frcp(float x)  { return __builtin_amdgcn_rcpf(x); }

// max(z,0) - z*t + log1p(exp(-|z|)) via HW exp2/log2
__device__ __forceinline__ float bce_fast(float z, float t) {
    const float e  = fexp2(-fabsf(z) * L2E);
    const float sp = LN2 * flog2(1.0f + e);
    return fmaxf(z, 0.0f) - z * t + sp;
}

__device__ __forceinline__ float sigmoid_fast(float z) {
    return frcp(1.0f + fexp2(-z * L2E));
}

__global__ __launch_bounds__(BLK, 6) void yolo_loss_main(
    const float* __restrict__ input,
    const float* __restrict__ mask,
    const float* __restrict__ obj_mask,
    const float* __restrict__ tx,
    const float* __restrict__ ty,
    const float* __restrict__ tw,
    const float* __restrict__ th,
    const float* __restrict__ tgt_scale,
    const float* __restrict__ tcls,
    float* __restrict__ ws)
{
    __shared__ float red[4][4];
    const int tid  = threadIdx.x;
    const int lane = tid & 63;
    const int wid  = tid >> 6;
    const int bid  = blockIdx.x;

    if (bid < NBLK_CLS) {
        // ---- class-BCE: 64 cells/block, tcls staged via LDS (contiguous) ----
        __shared__ float tl2[NC * PADS];            // [channel][cell], 20.8 KB
        const int B0    = bid * CLS_CB;             // first cell (64 | HW)
        const int plane = B0 / HW;
        const int hw0   = B0 % HW;

        // Phase 1: flat contiguous copy of 64*320B tcls slab -> LDS transposed
        const float* tslab = tcls + (size_t)B0 * NC;
        #pragma unroll
        for (int k = 0; k < 5; ++k) {
            const int c = tid + BLK * k;            // 16B-chunk id, 0..1279
            const float4 v = *(const float4*)(tslab + 4 * (size_t)c);
            const int qc = c / 20;                  // cell in block
            const int g  = c % 20;                  // chunk within cell
            tl2[(4 * g + 0) * PADS + qc] = v.x;
            tl2[(4 * g + 1) * PADS + qc] = v.y;
            tl2[(4 * g + 2) * PADS + qc] = v.z;
            tl2[(4 * g + 3) * PADS + qc] = v.w;
        }
        __syncthreads();

        // Phase 2: thread (q, p) does channels [20p, 20p+20) of cell B0+q
        const int q = tid >> 2;
        const int p = tid & 3;
        const float* zb = input + (size_t)plane * (5 + NC) * HW
                        + (size_t)(5 + 20 * p) * HW + hw0 + q;
        float z[20];
        #pragma unroll
        for (int i = 0; i < 20; ++i)
            z[i] = zb[(size_t)i * HW];              // 20 loads in flight
        float acc = 0.f;
        #pragma unroll
        for (int i = 0; i < 20; ++i)
            acc += bce_fast(z[i], tl2[(20 * p + i) * PADS + q]);
        float v = mask[B0 + q] * acc;

        #pragma unroll
        for (int off = 32; off > 0; off >>= 1)
            v += __shfl_down(v, off, 64);
        if (lane == 0) red[wid][0] = v;
        __syncthreads();
        if (tid == 0)
            ws[WS_CLS + bid] = red[0][0] + red[1][0] + red[2][0] + red[3][0];

    } else {
        // ------- box/conf/CIOU path: one cell per thread (coalesced) -------
        const int bbid  = bid - NBLK_CLS;
        const int cell  = bbid * BLK + tid;
        const int hw    = cell % HW;
        const int plane = cell / HW;

        const float* pbase = input + (size_t)plane * (5 + NC) * HW + hw;

        const float zx = pbase[0 * HW];
        const float zy = pbase[1 * HW];
        const float pw = pbase[2 * HW];
        const float ph = pbase[3 * HW];
        const float zc = pbase[4 * HW];

        const float m  = mask[cell];
        const float om = obj_mask[cell];
        const float gx = tx[cell];
        const float gy = ty[cell];
        const float gw = tw[cell];
        const float gh = th[cell];
        const float ts = tgt_scale[cell];

        const float x = sigmoid_fast(zx);
        const float y = sigmoid_fast(zy);

        float s_xy  = ts * (fabsf(x - gx) + fabsf(y - gy));
        float s_wh  = ts * (fabsf(pw - gw) + fabsf(ph - gh));
        float s_conf = om * bce_fast(zc, m);
        float s_iou;
        {
            const float p_x1 = x - pw * 0.5f, p_x2 = x + pw * 0.5f;
            const float p_y1 = y - ph * 0.5f, p_y2 = y + ph * 0.5f;
            const float g_x1 = gx - gw * 0.5f, g_x2 = gx + gw * 0.5f;
            const float g_y1 = gy - gh * 0.5f, g_y2 = gy + gh * 0.5f;

            const float iw = fmaxf(fminf(p_x2, g_x2) - fmaxf(p_x1, g_x1), 0.0f);
            const float ih = fmaxf(fminf(p_y2, g_y2) - fmaxf(p_y1, g_y1), 0.0f);
            const float inter = iw * ih;
            const float uni   = pw * ph + gw * gh - inter + EPSL;
            const float iou   = inter * frcp(uni);

            const float cw = fmaxf(p_x2, g_x2) - fminf(p_x1, g_x1);
            const float ch = fmaxf(p_y2, g_y2) - fminf(p_y1, g_y1);
            const float c2 = cw * cw + ch * ch + EPSL;
            const float rho2 = (x - gx) * (x - gx) + (y - gy) * (y - gy);

            const float da = atanf(gw * frcp(gh + EPSL))
                           - atanf(pw * frcp(ph + EPSL));
            const float v  = (4.0f / (float)(M_PI * M_PI)) * da * da;
            const float alpha = v * frcp(v - iou + 1.0f + EPSL);

            const float lbox = 1.0f - (iou - (rho2 * frcp(c2) + v * alpha));
            s_iou = m * ts * lbox;
        }

        float vals[4] = { s_xy, s_wh, s_iou, s_conf };
        #pragma unroll
        for (int j = 0; j < 4; ++j) {
            float v = vals[j];
            #pragma unroll
            for (int off = 32; off > 0; off >>= 1)
                v += __shfl_down(v, off, 64);
            vals[j] = v;
        }
        if (lane == 0) {
            #pragma unroll
            for (int j = 0; j < 4; ++j) red[wid][j] = vals[j];
        }
        __syncthreads();
        if (tid == 0) {
            #pragma unroll
            for (int j = 0; j < 4; ++j)
                ws[(size_t)bbid * 4 + j] =
                    red[0][j] + red[1][j] + red[2][j] + red[3][j];
        }
    }
}

// Deterministic final reduction: one block, fixed order -> identical every replay.
__global__ __launch_bounds__(BLK) void yolo_loss_final(
    const float* __restrict__ ws, float* __restrict__ out)
{
    __shared__ float red[4];
    const int lane = threadIdx.x & 63;
    const int wid  = threadIdx.x >> 6;
    const float scale4[4] = { 1.0f / (BSZ * BSZ), 1.0f / (BSZ * BSZ),
                              1.0f / BSZ, 1.0f / BSZ };

    for (int j = 0; j < 4; ++j) {
        float v = 0.f;
        for (int i = threadIdx.x; i < NBLK_BOX; i += BLK)
            v += ws[(size_t)i * 4 + j];
        #pragma unroll
        for (int off = 32; off > 0; off >>= 1)
            v += __shfl_down(v, off, 64);
        if (lane == 0) red[wid] = v;
        __syncthreads();
        if (threadIdx.x == 0)
            out[j] = (red[0] + red[1] + red[2] + red[3]) * scale4[j];
        __syncthreads();
    }
    {
        float v = 0.f;
        for (int i = threadIdx.x; i < NBLK_CLS; i += BLK)
            v += ws[WS_CLS + i];
        #pragma unroll
        for (int off = 32; off > 0; off >>= 1)
            v += __shfl_down(v, off, 64);
        if (lane == 0) red[wid] = v;
        __syncthreads();
        if (threadIdx.x == 0)
            out[4] = (red[0] + red[1] + red[2] + red[3]) * (1.0f / BSZ);
    }
}

extern "C" void kernel_launch(void* const* d_in, const int* in_sizes, int n_in,
                              void* d_out, int out_size, void* d_ws, size_t ws_size,
                              hipStream_t stream) {
    const float* input     = (const float*)d_in[0];
    const float* mask      = (const float*)d_in[1];
    const float* obj_mask  = (const float*)d_in[2];
    const float* tx        = (const float*)d_in[3];
    const float* ty        = (const float*)d_in[4];
    const float* tw        = (const float*)d_in[5];
    const float* th        = (const float*)d_in[6];
    const float* tgt_scale = (const float*)d_in[7];
    const float* tcls      = (const float*)d_in[8];
    float* out = (float*)d_out;
    float* ws  = (float*)d_ws;   // needs (4800 + 4800)*4 = 38400 bytes

    yolo_loss_main<<<NBLK_TOT, BLK, 0, stream>>>(
        input, mask, obj_mask, tx, ty, tw, th, tgt_scale, tcls, ws);
    yolo_loss_final<<<1, BLK, 0, stream>>>(ws, out);
}